// Round 2
// baseline (99.084 us; speedup 1.0000x reference)
//
#include <hip/hip_runtime.h>

// ScoreNet fused: central moments -> MLP -> analytic jacobian contraction.
// Round 6: hoist all sample-independent work out of the per-block path.
//  (a) Time embedding (sin/cos + 64x64 matmul) moved to a 64-thread
//      pre-kernel writing emb[64] + rsqrt(t) into d_ws: removes 33 MB/iter
//      of embW L2 streaming, the sinf/cosf dependent chain, the s_f/s_emb
//      LDS round-trip, and 2 of the 4 block barriers. With no barrier ahead
//      of h1 anymore, the compiler can hoist W1/x loads to the kernel top.
//  (b) W2b (6 KB) staged once per block into LDS transposed [12][128]
//      (stride-2 float2 reads, conflict-free), covered by the existing s_a
//      barrier: cuts W2b L2 traffic 4x (50 MB -> 12.5 MB/iter).
// r5 evidence: kernel portion ~15.5us vs ~4-5us of VALU work -> latency/L2
// bound; weight re-streaming from same addresses (L2 hotspot) is the theory.

static __device__ __forceinline__ float gelu_f(float x) {
    // Abramowitz-Stegun 7.1.26 erf (max err 1.5e-7), branch-free.
    float y = 0.7071067811865475f * x;
    float s = fabsf(y);
    float t = __builtin_amdgcn_rcpf(fmaf(0.3275911f, s, 1.0f));
    float p = t * fmaf(t, fmaf(t, fmaf(t, fmaf(t, 1.061405429f,
                    -1.453152027f), 1.421413741f), -0.284496736f), 0.254829592f);
    float e = __expf(-y * y);
    float ea = fmaf(-p, e, 1.0f);
    float erfv = copysignf(ea, y);
    return 0.5f * x * (1.0f + erfv);
}

// Wave64 sum via DPP: row_shr 1/2/4/8 accumulates lane 15 (mod 16) = row sum,
// row_bcast:15 folds rows 0->1, 2->3; row_bcast:31 folds halves; lane 63 has
// the total. bound_ctrl=true: invalid-source lanes read 0 (harmless for +).
#define DPP_ADD(v, ctrl) \
    v += __int_as_float(__builtin_amdgcn_update_dpp(0, __float_as_int(v), ctrl, 0xf, 0xf, true))

static __device__ __forceinline__ float wave_sum(float v) {
    DPP_ADD(v, 0x111);  // row_shr:1
    DPP_ADD(v, 0x112);  // row_shr:2
    DPP_ADD(v, 0x114);  // row_shr:4
    DPP_ADD(v, 0x118);  // row_shr:8
    DPP_ADD(v, 0x142);  // row_bcast:15
    DPP_ADD(v, 0x143);  // row_bcast:31
    return __int_as_float(__builtin_amdgcn_readlane(__float_as_int(v), 63));
}

#define TWO_PI_F 6.283185307179586f

// --- Pre-kernel: sample-independent time embedding, once per launch. ---
// ws[0..63] = emb = concat(sin, cos) @ embW + embB;  ws[64] = rsqrt(t).
__global__ __launch_bounds__(64) void emb_precompute(
    const float* __restrict__ t_in,   // [1]
    const float* __restrict__ Wf,     // [32]
    const float* __restrict__ embW,   // [64,64]
    const float* __restrict__ embB,   // [64]
    float* __restrict__ ws)
{
    __shared__ float s_f[64];
    const int tid = threadIdx.x;
    const float tval = t_in[0];
    if (tid < 32) {
        float xp = tval * Wf[tid] * TWO_PI_F;
        s_f[tid]      = sinf(xp);
        s_f[tid + 32] = cosf(xp);
    }
    __syncthreads();
    float acc = embB[tid];
    const float4* f4 = reinterpret_cast<const float4*>(s_f);
    #pragma unroll
    for (int c = 0; c < 16; ++c) {
        float4 a4 = f4[c];
        int j = 4 * c;
        acc = fmaf(a4.x, embW[(j+0)*64 + tid],
              fmaf(a4.y, embW[(j+1)*64 + tid],
              fmaf(a4.z, embW[(j+2)*64 + tid],
              fmaf(a4.w, embW[(j+3)*64 + tid], acc))));
    }
    ws[tid] = acc;
    if (tid == 0) ws[64] = rsqrtf(tval);
}

__global__ __launch_bounds__(256) void scorenet_fused(
    const float* __restrict__ x,      // [B,100,2]
    const float* __restrict__ emb_ws, // [65]: emb[64], rsqrt(t)
    const float* __restrict__ W1,     // [12,64]
    const float* __restrict__ b1,     // [64]
    const float* __restrict__ W2a,    // [64,128]
    const float* __restrict__ b2a,    // [128]
    const float* __restrict__ W2b,    // [128,12]
    const float* __restrict__ b2b,    // [12]
    const float* __restrict__ W2c,    // [12,12]
    const float* __restrict__ b2c,    // [12]
    float* __restrict__ out,          // [B,100,2]
    int B)
{
    __shared__ float s_a[64][4];           // h1 activations transposed: [j][sample]
    __shared__ float s_part[4][2][4][64];  // h2 partials: [sample][even/odd][wave][lane]
    __shared__ float s_w2bT[12][128];      // W2b transposed: [col][row]

    const int tid = threadIdx.x;
    const int lane = tid & 63;
    const int w = tid >> 6;

    const int b = blockIdx.x * 4 + w;
    const bool valid = b < B;
    const int bc = valid ? b : B - 1;     // clamp: no early return (barriers below)

    // Issue this sample's point loads immediately (HBM latency hides under
    // the weight staging / moments phase).
    const float2* px = reinterpret_cast<const float2*>(x) + (size_t)bc * 100;
    const bool has2 = lane < 36;
    float2 p0 = px[lane];
    float2 p1 = px[has2 ? lane + 64 : lane];

    // Stage W2b (transposed) into LDS once per block. Coalesced global reads;
    // the s_a barrier below covers completion before h3 reads it.
    #pragma unroll
    for (int i = tid; i < 1536; i += 256) {
        int row = i / 12, col = i - row * 12;
        s_w2bT[col][row] = W2b[i];
    }

    const float emb_lane = emb_ws[lane];
    const float rst = emb_ws[64];

    float xa = p0.x, ya = p0.y;
    float xb = has2 ? p1.x : 0.0f;
    float yb = has2 ? p1.y : 0.0f;

    // ---- mean over 100 points (DPP wave sums -> uniform scalars)
    const float mux = wave_sum(xa + xb) * 0.01f;
    const float muy = wave_sum(ya + yb) * 0.01f;

    float ua = xa - mux, va = ya - muy;
    float ub = has2 ? (xb - mux) : 0.0f;   // zero => contributes 0 to all monomials
    float vb = has2 ? (yb - muy) : 0.0f;

    // ---- 12 central-moment monomial sums
    // order: (1,1)(2,0)(0,2)(2,1)(1,2)(3,0)(0,3)(2,2)(3,1)(1,3)(4,0)(0,4)
    float ms[12];
    {
        float u2 = ua * ua, v2 = va * va;
        ms[0] = ua * va;   ms[1] = u2;        ms[2] = v2;
        ms[3] = u2 * va;   ms[4] = ua * v2;
        ms[5] = u2 * ua;   ms[6] = v2 * va;
        ms[7] = u2 * v2;   ms[8] = ms[5] * va; ms[9] = ua * ms[6];
        ms[10] = u2 * u2;  ms[11] = v2 * v2;
        float w2 = ub * ub, z2 = vb * vb;
        ms[0] += ub * vb;  ms[1] += w2;       ms[2] += z2;
        ms[3] += w2 * vb;  ms[4] += ub * z2;
        ms[5] += w2 * ub;  ms[6] += z2 * vb;
        ms[7] += w2 * z2;  ms[8] += w2 * ub * vb; ms[9] += ub * z2 * vb;
        ms[10] += w2 * w2; ms[11] += z2 * z2;
    }
    float m[12];   // wave-uniform (SGPR) after DPP reduction
    #pragma unroll
    for (int k = 0; k < 12; ++k) m[k] = wave_sum(ms[k]);

    // ---- MLP: h1 = gelu(m @ W1 + b1) + emb; lane owns unit `lane`
    float a1 = b1[lane];
    #pragma unroll
    for (int k = 0; k < 12; ++k) a1 = fmaf(m[k], W1[k * 64 + lane], a1);
    float aval = gelu_f(a1) + emb_lane;

    // ---- h2 = gelu((h1+emb) @ W2a + b2a), block-cooperative.
    // Stage all 4 samples' activations (transposed) in LDS, then wave w
    // handles j in [16w, 16w+16) for ALL 4 samples: W2a is read once per
    // BLOCK (32KB) instead of once per wave (128KB). Lane owns outputs
    // 2*lane, 2*lane+1 so W2a loads are float2-packed & coalesced.
    s_a[lane][w] = aval;            // one 8-way-conflict write: negligible
    __syncthreads();

    float4 plo = {0.f, 0.f, 0.f, 0.f};   // partial h2[o=2*lane], samples 0..3
    float4 phi = {0.f, 0.f, 0.f, 0.f};   // partial h2[o=2*lane+1]
    {
        const float4* a4p = reinterpret_cast<const float4*>(&s_a[0][0]);
        const float2* w2a2 = reinterpret_cast<const float2*>(W2a);
        #pragma unroll
        for (int jj = 0; jj < 16; ++jj) {
            const int j = (w << 4) + jj;
            float4 a4 = a4p[j];              // broadcast read: a_j for 4 samples
            float2 ww = w2a2[j * 64 + lane]; // W2a[j][2l], W2a[j][2l+1]
            plo.x = fmaf(a4.x, ww.x, plo.x);
            plo.y = fmaf(a4.y, ww.x, plo.y);
            plo.z = fmaf(a4.z, ww.x, plo.z);
            plo.w = fmaf(a4.w, ww.x, plo.w);
            phi.x = fmaf(a4.x, ww.y, phi.x);
            phi.y = fmaf(a4.y, ww.y, phi.y);
            phi.z = fmaf(a4.z, ww.y, phi.z);
            phi.w = fmaf(a4.w, ww.y, phi.w);
        }
    }
    s_part[0][0][w][lane] = plo.x;
    s_part[1][0][w][lane] = plo.y;
    s_part[2][0][w][lane] = plo.z;
    s_part[3][0][w][lane] = plo.w;
    s_part[0][1][w][lane] = phi.x;
    s_part[1][1][w][lane] = phi.y;
    s_part[2][1][w][lane] = phi.z;
    s_part[3][1][w][lane] = phi.w;
    __syncthreads();

    // Wave w reduces its own sample's 4 partials. o_even = 2*lane, o_odd = 2*lane+1.
    const float2 bb2a = reinterpret_cast<const float2*>(b2a)[lane];
    float acc0 = bb2a.x + ((s_part[w][0][0][lane] + s_part[w][0][1][lane])
                         + (s_part[w][0][2][lane] + s_part[w][0][3][lane]));
    float acc1 = bb2a.y + ((s_part[w][1][0][lane] + s_part[w][1][1][lane])
                         + (s_part[w][1][2][lane] + s_part[w][1][3][lane]));
    float h2lo = gelu_f(acc0), h2hi = gelu_f(acc1);   // units 2*lane, 2*lane+1

    // ---- h3 = gelu(h2 @ W2b + b2b): W2b from LDS (staged once per block),
    // transposed layout -> stride-2 float2 reads, conflict-free.
    float h3[12];  // wave-uniform
    #pragma unroll
    for (int k = 0; k < 12; ++k) {
        float2 wk = *reinterpret_cast<const float2*>(&s_w2bT[k][2 * lane]);
        float p3 = fmaf(h2lo, wk.x, h2hi * wk.y);
        h3[k] = gelu_f(wave_sum(p3) + b2b[k]);
    }

    // ---- h = (h3 @ W2c + b2c) / sqrt(t): lane-parallel (lanes 0..11) then
    // readlane back to uniform — replaces 144 redundant wave-uniform FMAs.
    float hk = 0.0f;
    if (lane < 12) {
        hk = b2c[lane];
        #pragma unroll
        for (int j = 0; j < 12; ++j) hk = fmaf(h3[j], W2c[j * 12 + lane], hk);
        hk *= rst;
    }
    float h[12];
    #pragma unroll
    for (int k = 0; k < 12; ++k)
        h[k] = __int_as_float(__builtin_amdgcn_readlane(__float_as_int(hk), k));

    // ---- per-sample correction constants (mean-shift term of the jacobian).
    // S0_k = sum u^(P-1) v^Q: degree-1 sums vanish (centered); others are moments.
    const float inv_n = 0.01f;
    float c0 = (2.0f*h[3]*m[0] + h[4]*m[2] + 3.0f*h[5]*m[1] + 2.0f*h[7]*m[4]
              + 3.0f*h[8]*m[3] + h[9]*m[6] + 4.0f*h[10]*m[5]) * inv_n;
    float c1 = (h[3]*m[1] + 2.0f*h[4]*m[0] + 3.0f*h[6]*m[2] + 2.0f*h[7]*m[3]
              + h[8]*m[5] + 3.0f*h[9]*m[4] + 4.0f*h[11]*m[6]) * inv_n;

    // cubic polynomial coefficients in (u, v) — all wave-uniform
    const float A1 = 2.0f*h[1], A2 = h[0],      A3 = 3.0f*h[5], A4 = 2.0f*h[3], A5 = h[4];
    const float A6 = 4.0f*h[10],A7 = 3.0f*h[8], A8 = 2.0f*h[7], A9 = h[9];
    const float B1 = h[0],      B2 = 2.0f*h[2], B3 = h[3],      B4 = 2.0f*h[4], B5 = 3.0f*h[6];
    const float B6 = h[8],      B7 = 2.0f*h[7], B8 = 3.0f*h[9], B9 = 4.0f*h[11];

    float2* pout = reinterpret_cast<float2*>(out) + (size_t)bc * 100;
    if (valid) {
        float u = ua, v = va;
        float u2 = u*u, v2 = v*v;
        float o0 = A1*u + A2*v + A3*u2 + A4*u*v + A5*v2 + A6*u2*u + A7*u2*v + A8*u*v2 + A9*v2*v - c0;
        float o1 = B1*u + B2*v + B3*u2 + B4*u*v + B5*v2 + B6*u2*u + B7*u2*v + B8*u*v2 + B9*v2*v - c1;
        float2 r; r.x = o0; r.y = o1;
        pout[lane] = r;
        if (has2) {
            float uu = ub, vv = vb;
            float uu2 = uu*uu, vv2 = vv*vv;
            float q0 = A1*uu + A2*vv + A3*uu2 + A4*uu*vv + A5*vv2 + A6*uu2*uu + A7*uu2*vv + A8*uu*vv2 + A9*vv2*vv - c0;
            float q1 = B1*uu + B2*vv + B3*uu2 + B4*uu*vv + B5*vv2 + B6*uu2*uu + B7*uu2*vv + B8*uu*vv2 + B9*vv2*vv - c1;
            float2 r2; r2.x = q0; r2.y = q1;
            pout[lane + 64] = r2;
        }
    }
}

extern "C" void kernel_launch(void* const* d_in, const int* in_sizes, int n_in,
                              void* d_out, int out_size, void* d_ws, size_t ws_size,
                              hipStream_t stream) {
    const float* x    = (const float*)d_in[0];
    const float* t    = (const float*)d_in[1];
    // d_in[2] = K (exponent table) — baked into the kernel as compile-time constants.
    const float* Wf   = (const float*)d_in[3];
    const float* embW = (const float*)d_in[4];
    const float* embB = (const float*)d_in[5];
    const float* W1   = (const float*)d_in[6];
    const float* b1   = (const float*)d_in[7];
    const float* W2a  = (const float*)d_in[8];
    const float* b2a  = (const float*)d_in[9];
    const float* W2b  = (const float*)d_in[10];
    const float* b2b  = (const float*)d_in[11];
    const float* W2c  = (const float*)d_in[12];
    const float* b2c  = (const float*)d_in[13];

    const int B = in_sizes[0] / 200;            // [B,100,2]
    const int blocks = (B + 3) / 4;             // 4 samples (waves) per block
    float* ws = (float*)d_ws;                   // 65 floats: emb[64], rsqrt(t)

    emb_precompute<<<1, 64, 0, stream>>>(t, Wf, embW, embB, ws);
    scorenet_fused<<<blocks, 256, 0, stream>>>(
        x, ws, W1, b1, W2a, b2a, W2b, b2b, W2c, b2c,
        (float*)d_out, B);
}

// Round 3
// 95.993 us; speedup vs baseline: 1.0322x; 1.0322x over previous
//
#include <hip/hip_runtime.h>

// ScoreNet fused: central moments -> MLP -> analytic jacobian contraction.
// Round 7: revert r6's pre-kernel (launch overhead > hoisting gain; 96.5->99.1).
// Instead attack per-block serial structure:
//  (a) 2 sample-groups per block (1024 blocks x 8 samples): emb matmul, s_f,
//      W2b staging amortized 2x; both groups' x loads issued at kernel top.
//  (b) emb matmul spread across all 256 threads (16-term partial per thread,
//      LDS reduce at use) instead of a 64-deep chain on one wave; overlaps
//      with W2b staging between the same barrier pair.
//  (c) keep r6b: W2b staged transposed in LDS once per block.
// r5 evidence: kernel ~15.5us vs ~5.3us VALU floor; fills are a fixed 81us.

static __device__ __forceinline__ float gelu_f(float x) {
    // Abramowitz-Stegun 7.1.26 erf (max err 1.5e-7), branch-free.
    float y = 0.7071067811865475f * x;
    float s = fabsf(y);
    float t = __builtin_amdgcn_rcpf(fmaf(0.3275911f, s, 1.0f));
    float p = t * fmaf(t, fmaf(t, fmaf(t, fmaf(t, 1.061405429f,
                    -1.453152027f), 1.421413741f), -0.284496736f), 0.254829592f);
    float e = __expf(-y * y);
    float ea = fmaf(-p, e, 1.0f);
    float erfv = copysignf(ea, y);
    return 0.5f * x * (1.0f + erfv);
}

// Wave64 sum via DPP: row_shr 1/2/4/8 accumulates lane 15 (mod 16) = row sum,
// row_bcast:15 folds rows 0->1, 2->3; row_bcast:31 folds halves; lane 63 has
// the total. bound_ctrl=true: invalid-source lanes read 0 (harmless for +).
#define DPP_ADD(v, ctrl) \
    v += __int_as_float(__builtin_amdgcn_update_dpp(0, __float_as_int(v), ctrl, 0xf, 0xf, true))

static __device__ __forceinline__ float wave_sum(float v) {
    DPP_ADD(v, 0x111);  // row_shr:1
    DPP_ADD(v, 0x112);  // row_shr:2
    DPP_ADD(v, 0x114);  // row_shr:4
    DPP_ADD(v, 0x118);  // row_shr:8
    DPP_ADD(v, 0x142);  // row_bcast:15
    DPP_ADD(v, 0x143);  // row_bcast:31
    return __int_as_float(__builtin_amdgcn_readlane(__float_as_int(v), 63));
}

#define TWO_PI_F 6.283185307179586f

__global__ __launch_bounds__(256) void scorenet_fused(
    const float* __restrict__ x,      // [B,100,2]
    const float* __restrict__ t_in,   // [1]
    const float* __restrict__ Wf,     // [32]
    const float* __restrict__ embW,   // [64,64]
    const float* __restrict__ embB,   // [64]
    const float* __restrict__ W1,     // [12,64]
    const float* __restrict__ b1,     // [64]
    const float* __restrict__ W2a,    // [64,128]
    const float* __restrict__ b2a,    // [128]
    const float* __restrict__ W2b,    // [128,12]
    const float* __restrict__ b2b,    // [12]
    const float* __restrict__ W2c,    // [12,12]
    const float* __restrict__ b2c,    // [12]
    float* __restrict__ out,          // [B,100,2]
    int B)
{
    __shared__ float s_f[64];              // sin/cos fourier features
    __shared__ float s_epart[4][64];       // emb matmul partials per wave
    __shared__ float s_a[64][4];           // h1 activations transposed: [j][sample]
    __shared__ float s_part[4][2][4][64];  // h2 partials: [sample][even/odd][wave][lane]
    __shared__ float s_w2bT[12][128];      // W2b transposed: [col][row]

    const int tid = threadIdx.x;
    const int lane = tid & 63;
    const int w = tid >> 6;
    const float tval = t_in[0];

    // Two sample-groups per block: group g sample = blockIdx*8 + 4g + w.
    const int sb0 = blockIdx.x * 8 + w;
    const int sb1 = sb0 + 4;
    const bool v0 = sb0 < B, v1 = sb1 < B;
    const int c0i = v0 ? sb0 : B - 1;
    const int c1i = v1 ? sb1 : B - 1;

    // Issue ALL point loads for both groups immediately (HBM latency hides
    // under the staging + embedding phase).
    const bool has2 = lane < 36;
    const float2* px0 = reinterpret_cast<const float2*>(x) + (size_t)c0i * 100;
    const float2* px1 = reinterpret_cast<const float2*>(x) + (size_t)c1i * 100;
    float2 pA[2], pB[2];
    pA[0] = px0[lane];  pB[0] = px0[has2 ? lane + 64 : lane];
    pA[1] = px1[lane];  pB[1] = px1[has2 ? lane + 64 : lane];

    // Stage W2b (transposed) into LDS once per block; coalesced global reads.
    #pragma unroll
    for (int i = tid; i < 1536; i += 256) {
        int row = i / 12, col = i - row * 12;
        s_w2bT[col][row] = W2b[i];
    }

    // Fourier features (32 lanes), then barrier.
    if (tid < 32) {
        float xp = tval * Wf[tid] * TWO_PI_F;
        s_f[tid]      = sinf(xp);
        s_f[tid + 32] = cosf(xp);
    }
    __syncthreads();   // s_f ready

    // Emb matmul spread across all 256 threads: wave w sums j in [16w,16w+16).
    {
        float ep = 0.0f;
        #pragma unroll
        for (int jj = 0; jj < 16; ++jj) {
            int j = 16 * w + jj;
            ep = fmaf(s_f[j], embW[j * 64 + lane], ep);  // s_f: broadcast read
        }
        s_epart[w][lane] = ep;
    }
    __syncthreads();   // s_epart + s_w2bT ready

    const float embl = embB[lane]
        + ((s_epart[0][lane] + s_epart[1][lane])
         + (s_epart[2][lane] + s_epart[3][lane]));
    const float rst = rsqrtf(tval);

    const float2* w2a2 = reinterpret_cast<const float2*>(W2a);
    const float2 bb2a = reinterpret_cast<const float2*>(b2a)[lane];

    #pragma unroll
    for (int g = 0; g < 2; ++g) {
        const bool valid = g ? v1 : v0;
        const int bc = g ? c1i : c0i;

        float xa = pA[g].x, ya = pA[g].y;
        float xb = has2 ? pB[g].x : 0.0f;
        float yb = has2 ? pB[g].y : 0.0f;

        // ---- mean over 100 points (DPP wave sums -> uniform scalars)
        const float mux = wave_sum(xa + xb) * 0.01f;
        const float muy = wave_sum(ya + yb) * 0.01f;

        float ua = xa - mux, va = ya - muy;
        float ub = has2 ? (xb - mux) : 0.0f;   // zero => contributes 0 below
        float vb = has2 ? (yb - muy) : 0.0f;

        // ---- 12 central-moment monomial sums
        // order: (1,1)(2,0)(0,2)(2,1)(1,2)(3,0)(0,3)(2,2)(3,1)(1,3)(4,0)(0,4)
        float ms[12];
        {
            float u2 = ua * ua, v2 = va * va;
            ms[0] = ua * va;   ms[1] = u2;        ms[2] = v2;
            ms[3] = u2 * va;   ms[4] = ua * v2;
            ms[5] = u2 * ua;   ms[6] = v2 * va;
            ms[7] = u2 * v2;   ms[8] = ms[5] * va; ms[9] = ua * ms[6];
            ms[10] = u2 * u2;  ms[11] = v2 * v2;
            float w2 = ub * ub, z2 = vb * vb;
            ms[0] += ub * vb;  ms[1] += w2;       ms[2] += z2;
            ms[3] += w2 * vb;  ms[4] += ub * z2;
            ms[5] += w2 * ub;  ms[6] += z2 * vb;
            ms[7] += w2 * z2;  ms[8] += w2 * ub * vb; ms[9] += ub * z2 * vb;
            ms[10] += w2 * w2; ms[11] += z2 * z2;
        }
        float m[12];   // wave-uniform after DPP reduction
        #pragma unroll
        for (int k = 0; k < 12; ++k) m[k] = wave_sum(ms[k]);

        // ---- h1 = gelu(m @ W1 + b1) + emb; lane owns unit `lane`
        float a1 = b1[lane];
        #pragma unroll
        for (int k = 0; k < 12; ++k) a1 = fmaf(m[k], W1[k * 64 + lane], a1);
        float aval = gelu_f(a1) + embl;

        // ---- h2 = gelu((h1+emb) @ W2a + b2a), block-cooperative.
        // Wave w handles j in [16w,16w+16) for ALL 4 samples of this group:
        // W2a read once per block-group. Lane owns outputs 2l, 2l+1.
        s_a[lane][w] = aval;
        __syncthreads();   // s_a ready (also fences prior group's s_a reads)

        float4 plo = {0.f, 0.f, 0.f, 0.f};
        float4 phi = {0.f, 0.f, 0.f, 0.f};
        {
            const float4* a4p = reinterpret_cast<const float4*>(&s_a[0][0]);
            #pragma unroll
            for (int jj = 0; jj < 16; ++jj) {
                const int j = (w << 4) + jj;
                float4 a4 = a4p[j];              // broadcast: a_j for 4 samples
                float2 ww = w2a2[j * 64 + lane]; // W2a[j][2l], W2a[j][2l+1]
                plo.x = fmaf(a4.x, ww.x, plo.x);
                plo.y = fmaf(a4.y, ww.x, plo.y);
                plo.z = fmaf(a4.z, ww.x, plo.z);
                plo.w = fmaf(a4.w, ww.x, plo.w);
                phi.x = fmaf(a4.x, ww.y, phi.x);
                phi.y = fmaf(a4.y, ww.y, phi.y);
                phi.z = fmaf(a4.z, ww.y, phi.z);
                phi.w = fmaf(a4.w, ww.y, phi.w);
            }
        }
        s_part[0][0][w][lane] = plo.x;
        s_part[1][0][w][lane] = plo.y;
        s_part[2][0][w][lane] = plo.z;
        s_part[3][0][w][lane] = plo.w;
        s_part[0][1][w][lane] = phi.x;
        s_part[1][1][w][lane] = phi.y;
        s_part[2][1][w][lane] = phi.z;
        s_part[3][1][w][lane] = phi.w;
        __syncthreads();   // s_part ready

        // Wave w reduces its own sample's partials. o = 2*lane, 2*lane+1.
        float acc0 = bb2a.x + ((s_part[w][0][0][lane] + s_part[w][0][1][lane])
                             + (s_part[w][0][2][lane] + s_part[w][0][3][lane]));
        float acc1 = bb2a.y + ((s_part[w][1][0][lane] + s_part[w][1][1][lane])
                             + (s_part[w][1][2][lane] + s_part[w][1][3][lane]));
        float h2lo = gelu_f(acc0), h2hi = gelu_f(acc1);

        // ---- h3 = gelu(h2 @ W2b + b2b): W2b from LDS (staged once/block).
        float h3[12];  // wave-uniform
        #pragma unroll
        for (int k = 0; k < 12; ++k) {
            float2 wk = *reinterpret_cast<const float2*>(&s_w2bT[k][2 * lane]);
            float p3 = fmaf(h2lo, wk.x, h2hi * wk.y);
            h3[k] = gelu_f(wave_sum(p3) + b2b[k]);
        }

        // ---- h = (h3 @ W2c + b2c) / sqrt(t): lane-parallel (lanes 0..11),
        // then readlane back to uniform.
        float hk = 0.0f;
        if (lane < 12) {
            hk = b2c[lane];
            #pragma unroll
            for (int j = 0; j < 12; ++j) hk = fmaf(h3[j], W2c[j * 12 + lane], hk);
            hk *= rst;
        }
        float h[12];
        #pragma unroll
        for (int k = 0; k < 12; ++k)
            h[k] = __int_as_float(__builtin_amdgcn_readlane(__float_as_int(hk), k));

        // ---- per-sample correction constants (mean-shift jacobian term).
        const float inv_n = 0.01f;
        float cc0 = (2.0f*h[3]*m[0] + h[4]*m[2] + 3.0f*h[5]*m[1] + 2.0f*h[7]*m[4]
                   + 3.0f*h[8]*m[3] + h[9]*m[6] + 4.0f*h[10]*m[5]) * inv_n;
        float cc1 = (h[3]*m[1] + 2.0f*h[4]*m[0] + 3.0f*h[6]*m[2] + 2.0f*h[7]*m[3]
                   + h[8]*m[5] + 3.0f*h[9]*m[4] + 4.0f*h[11]*m[6]) * inv_n;

        // cubic polynomial coefficients in (u, v) — all wave-uniform
        const float A1 = 2.0f*h[1], A2 = h[0],      A3 = 3.0f*h[5], A4 = 2.0f*h[3], A5 = h[4];
        const float A6 = 4.0f*h[10],A7 = 3.0f*h[8], A8 = 2.0f*h[7], A9 = h[9];
        const float B1 = h[0],      B2 = 2.0f*h[2], B3 = h[3],      B4 = 2.0f*h[4], B5 = 3.0f*h[6];
        const float B6 = h[8],      B7 = 2.0f*h[7], B8 = 3.0f*h[9], B9 = 4.0f*h[11];

        float2* pout = reinterpret_cast<float2*>(out) + (size_t)bc * 100;
        if (valid) {
            float u = ua, v = va;
            float u2 = u*u, v2 = v*v;
            float o0 = A1*u + A2*v + A3*u2 + A4*u*v + A5*v2 + A6*u2*u + A7*u2*v + A8*u*v2 + A9*v2*v - cc0;
            float o1 = B1*u + B2*v + B3*u2 + B4*u*v + B5*v2 + B6*u2*u + B7*u2*v + B8*u*v2 + B9*v2*v - cc1;
            float2 r; r.x = o0; r.y = o1;
            pout[lane] = r;
            if (has2) {
                float uu = ub, vv = vb;
                float uu2 = uu*uu, vv2 = vv*vv;
                float q0 = A1*uu + A2*vv + A3*uu2 + A4*uu*vv + A5*vv2 + A6*uu2*uu + A7*uu2*vv + A8*uu*vv2 + A9*vv2*vv - cc0;
                float q1 = B1*uu + B2*vv + B3*uu2 + B4*uu*vv + B5*vv2 + B6*uu2*uu + B7*uu2*vv + B8*uu*vv2 + B9*vv2*vv - cc1;
                float2 r2; r2.x = q0; r2.y = q1;
                pout[lane + 64] = r2;
            }
        }
    }
}

extern "C" void kernel_launch(void* const* d_in, const int* in_sizes, int n_in,
                              void* d_out, int out_size, void* d_ws, size_t ws_size,
                              hipStream_t stream) {
    const float* x    = (const float*)d_in[0];
    const float* t    = (const float*)d_in[1];
    // d_in[2] = K (exponent table) — baked into the kernel as compile-time constants.
    const float* Wf   = (const float*)d_in[3];
    const float* embW = (const float*)d_in[4];
    const float* embB = (const float*)d_in[5];
    const float* W1   = (const float*)d_in[6];
    const float* b1   = (const float*)d_in[7];
    const float* W2a  = (const float*)d_in[8];
    const float* b2a  = (const float*)d_in[9];
    const float* W2b  = (const float*)d_in[10];
    const float* b2b  = (const float*)d_in[11];
    const float* W2c  = (const float*)d_in[12];
    const float* b2c  = (const float*)d_in[13];

    const int B = in_sizes[0] / 200;            // [B,100,2]
    const int blocks = (B + 7) / 8;             // 8 samples (2 groups of 4 waves)

    scorenet_fused<<<blocks, 256, 0, stream>>>(
        x, t, Wf, embW, embB, W1, b1, W2a, b2a, W2b, b2b, W2c, b2c,
        (float*)d_out, B);
}